// Round 18
// baseline (284.692 us; speedup 1.0000x reference)
//
#include <hip/hip_runtime.h>
#include <hip/hip_bf16.h>

#define N_NODES 40000
#define M_PAD   40064
#define N_EDGES 320000
#define DIM 128
#define HC 512
#define NHEAD 4
#define CHEAD 128
#define DEPTH_L 2
#define MLP_DIM 512
#define SCAN_NB ((N_NODES + 255) / 256)   // 157

typedef __attribute__((ext_vector_type(8))) short short8;
typedef __attribute__((ext_vector_type(4))) float f32x4;

static __device__ __forceinline__ void gload_lds16(const void* g, void* l)
{
    __builtin_amdgcn_global_load_lds(
        (const __attribute__((address_space(1))) unsigned int*)g,
        (__attribute__((address_space(3))) unsigned int*)l,
        16, 0, 0);
}

static __device__ __forceinline__ unsigned int packbf2(float a, float b)
{
    union { __hip_bfloat16 h[2]; unsigned int u; } p;
    p.h[0] = __float2bfloat16(a);
    p.h[1] = __float2bfloat16(b);
    return p.u;
}

// fast gelu: v * sigmoid(2z), z = 0.7978845608(v + 0.044715 v^3)
static __device__ __forceinline__ float gelu_f(float v)
{
    float z2 = -1.5957691216f * (v + 0.044715f * v * v * v);
    return v / (1.f + __expf(z2));
}

// ---------------- merged prep: wcvt(1024) | prep_u(16) | prep_m(512) |
//                  prep_c(64) | ae(2)  = 1618 blocks --------------------------
struct PrepArgs {
    const float* wsrc[4];
    __hip_bfloat16* wdst[4];
    int wK[4];
    int wN[4];
    const float* gat_W;
    const float* att_src;
    const float* att_dst;
    const float* edge_W;
    const float* att_edge;
    const float* gat_bias;
    const float* qf_W;
    const float* qf_b;
    float* uvec;
    __hip_bfloat16* Mt;
    float* cvec;
    float* ae;
};
__global__ __launch_bounds__(256) void k_prep(PrepArgs a)
{
    int b = blockIdx.x;
    int tid = threadIdx.x;
    if (b < 1024) {                         // weight convert+transpose (FF)
        int j = b >> 8;
        int i = (b & 255) * 256 + tid;
        int K = a.wK[j], N = a.wN[j];
        if (i < K * N) {
            int n = i / K, k = i % K;
            a.wdst[j][i] = __float2bfloat16(a.wsrc[j][(size_t)k * N + n]);
        }
    } else if (b < 1040) {                  // uvec
        if (tid < 128) {
            int bb = b - 1024;
            int d = bb >> 3, t8 = bb & 7;
            int t = t8 >> 2, h = t8 & 3;
            int c = tid;
            const float* W = a.gat_W + (size_t)d * DIM * HC;
            const float* av = (t == 0 ? a.att_src : a.att_dst)
                              + (size_t)d * NHEAD * CHEAD + h * CHEAD;
            float s = 0.f;
            for (int cc = 0; cc < CHEAD; ++cc)
                s += W[(size_t)c * HC + h * CHEAD + cc] * av[cc];
            a.uvec[(size_t)d * 1024 + t8 * 128 + c] = s;
        }
    } else if (b < 1552) {                  // Mt
        int i = (b - 1040) * 256 + tid;     // [d][hk][j]
        int d = i >> 16;
        int hk = (i >> 7) & 511;
        int j = i & 127;
        int h = hk >> 7, k = hk & 127;
        const float* W = a.gat_W + (size_t)d * DIM * HC + (size_t)k * HC + h * CHEAD;
        const float* Q = a.qf_W + (size_t)d * HC * DIM + (size_t)h * CHEAD * DIM + j;
        float s = 0.f;
        for (int c = 0; c < CHEAD; ++c)
            s += W[c] * Q[(size_t)c * DIM];
        a.Mt[(size_t)d * 65536 + (size_t)j * 512 + hk] = __float2bfloat16(s);
    } else if (b < 1616) {                  // cvec
        int idx = (b - 1552) * 4 + (tid >> 6);
        int lane = tid & 63;
        int d = idx >> 7, j = idx & 127;
        float s = 0.f;
        for (int m = lane; m < HC; m += 64)
            s += a.gat_bias[(size_t)d * HC + m]
               * a.qf_W[(size_t)d * HC * DIM + (size_t)m * DIM + j];
        #pragma unroll
        for (int dd = 32; dd; dd >>= 1) s += __shfl_xor(s, dd);
        if (lane == 0) a.cvec[idx] = s + a.qf_b[(size_t)d * DIM + j];
    } else {                                // ae
        int d = b - 1616;
        int h = tid >> 6, lane = tid & 63;
        float2 w = *reinterpret_cast<const float2*>(
            a.edge_W + (size_t)d * HC + h * CHEAD + lane * 2);
        float2 av = *reinterpret_cast<const float2*>(
            a.att_edge + (size_t)d * NHEAD * CHEAD + h * CHEAD + lane * 2);
        float s = w.x * av.x + w.y * av.y;
        #pragma unroll
        for (int dd = 32; dd; dd >>= 1) s += __shfl_xor(s, dd);
        if (lane == 0) a.ae[d * 4 + h] = s;
    }
}

// ---------------- CSR build (parallel 3-pass scan; proven chain) -------------
__global__ void k_hist(const int* __restrict__ dst, int* __restrict__ deg)
{
    int e = blockIdx.x * 256 + threadIdx.x;
    if (e < N_EDGES) atomicAdd(&deg[dst[e]], 1);
}

__global__ __launch_bounds__(256) void k_scan1(const int* __restrict__ deg,
                                               int* __restrict__ off,
                                               int* __restrict__ bsum)
{
    __shared__ int wsum[4];
    int b = blockIdx.x;
    int t = threadIdx.x, lane = t & 63, w = t >> 6;
    int i = b * 256 + t;
    int v = (i < N_NODES) ? deg[i] : 0;
    int s = v;
    #pragma unroll
    for (int d = 1; d < 64; d <<= 1) {
        int u = __shfl_up(s, d);
        if (lane >= d) s += u;
    }
    if (lane == 63) wsum[w] = s;
    __syncthreads();
    int wpre = 0;
    #pragma unroll
    for (int j = 0; j < 4; ++j)
        if (j < w) wpre += wsum[j];
    if (i < N_NODES) off[i] = wpre + s - v;
    if (t == 255) bsum[b] = wpre + s;
}

__global__ __launch_bounds__(256) void k_scan2(int* __restrict__ bsum,
                                               int* __restrict__ bpre)
{
    __shared__ int wsum[4];
    int t = threadIdx.x, lane = t & 63, w = t >> 6;
    int v = (t < SCAN_NB) ? bsum[t] : 0;
    int s = v;
    #pragma unroll
    for (int d = 1; d < 64; d <<= 1) {
        int u = __shfl_up(s, d);
        if (lane >= d) s += u;
    }
    if (lane == 63) wsum[w] = s;
    __syncthreads();
    int wpre = 0;
    #pragma unroll
    for (int j = 0; j < 4; ++j)
        if (j < w) wpre += wsum[j];
    if (t < SCAN_NB) bpre[t] = wpre + s - v;
    if (t == 255) bpre[SCAN_NB] = wpre + s;   // grand total
}

__global__ __launch_bounds__(256) void k_scan3(int* __restrict__ off,
                                               const int* __restrict__ bpre,
                                               int* __restrict__ cur)
{
    int b = blockIdx.x;
    int i = b * 256 + threadIdx.x;
    if (i < N_NODES) {
        int o = off[i] + bpre[b];
        off[i] = o;
        cur[i] = o;
    }
    if (i == 0) off[N_NODES] = bpre[SCAN_NB];
}

__global__ void k_fill(const int* __restrict__ src, const int* __restrict__ dst,
                       const float* __restrict__ ea, int* __restrict__ cur,
                       int* __restrict__ scsr, int* __restrict__ dcsr,
                       float* __restrict__ eacsr)
{
    int e = blockIdx.x * 256 + threadIdx.x;
    if (e < N_EDGES) {
        int dd = dst[e];
        int p = atomicAdd(&cur[dd], 1);
        scsr[p] = src[e];
        dcsr[p] = dd;
        eacsr[p] = ea[e];
    }
}

// ---------------- LayerNorm + fused attention dots (initial) -----------------
__global__ __launch_bounds__(256) void k_ln(const float* __restrict__ x,
                                            const float* __restrict__ gma,
                                            const float* __restrict__ bta,
                                            const float* __restrict__ uvec,
                                            __hip_bfloat16* __restrict__ out,
                                            float* __restrict__ asrc,
                                            float* __restrict__ adst, int M)
{
    int row = blockIdx.x * 4 + (threadIdx.x >> 6);
    int lane = threadIdx.x & 63;
    if (row >= M) return;
    float2 v = *reinterpret_cast<const float2*>(x + (size_t)row * DIM + lane * 2);
    float s = v.x + v.y, sq = v.x * v.x + v.y * v.y;
    #pragma unroll
    for (int d = 32; d; d >>= 1) { s += __shfl_xor(s, d); sq += __shfl_xor(sq, d); }
    float mean = s * (1.f / DIM);
    float var = sq * (1.f / DIM) - mean * mean;
    float rs = rsqrtf(var + 1e-5f);
    int c = lane * 2;
    float h0 = (v.x - mean) * rs * gma[c] + bta[c];
    float h1 = (v.y - mean) * rs * gma[c + 1] + bta[c + 1];
    *reinterpret_cast<unsigned int*>(out + (size_t)row * DIM + c) = packbf2(h0, h1);
    // fused dots: 8 targets (4 src-heads, 4 dst-heads)
    float ss[8];
    #pragma unroll
    for (int tt = 0; tt < 8; ++tt) {
        float2 uv = *reinterpret_cast<const float2*>(uvec + tt * 128 + c);
        ss[tt] = h0 * uv.x + h1 * uv.y;
    }
    #pragma unroll
    for (int d = 32; d; d >>= 1) {
        #pragma unroll
        for (int tt = 0; tt < 8; ++tt) ss[tt] += __shfl_xor(ss[tt], d);
    }
    if (lane == 0) {
        reinterpret_cast<float4*>(asrc)[row] = make_float4(ss[0], ss[1], ss[2], ss[3]);
        reinterpret_cast<float4*>(adst)[row] = make_float4(ss[4], ss[5], ss[6], ss[7]);
    }
}

// ---------------- streaming per-edge weights (CSR order, coalesced) ----------
__global__ __launch_bounds__(256) void k_alpha(const int* __restrict__ scsr,
                                               const int* __restrict__ dcsr,
                                               const float* __restrict__ eacsr,
                                               const float* __restrict__ asrc,
                                               const float* __restrict__ adst,
                                               const float* __restrict__ ae4v,
                                               float* __restrict__ wcsr)
{
    int p = blockIdx.x * 256 + threadIdx.x;
    if (p >= N_EDGES) return;
    int s = scsr[p], dd = dcsr[p];
    float q = eacsr[p];
    float4 as = reinterpret_cast<const float4*>(asrc)[s];
    float4 ad = reinterpret_cast<const float4*>(adst)[dd];
    float4 ae = *reinterpret_cast<const float4*>(ae4v);
    float4 w;
    float al;
    al = as.x + ad.x + ae.x * q; al = al > 0.f ? al : 0.2f * al; w.x = __expf(al);
    al = as.y + ad.y + ae.y * q; al = al > 0.f ? al : 0.2f * al; w.y = __expf(al);
    al = as.z + ad.z + ae.z * q; al = al > 0.f ? al : 0.2f * al; w.z = __expf(al);
    al = as.w + ad.w + ae.w * q; al = al > 0.f ? al : 0.2f * al; w.w = __expf(al);
    reinterpret_cast<float4*>(wcsr)[p] = w;
}

// ---------------- input-space aggregate: 4 sequential edge chains in flight --
__global__ __launch_bounds__(256) void k_agg2(const int* __restrict__ off,
                                              const int* __restrict__ scsr,
                                              const float* __restrict__ wcsr,
                                              const unsigned int* __restrict__ hln,
                                              unsigned int* __restrict__ agg)
{
    int n = blockIdx.x * 4 + (threadIdx.x >> 6);
    int lane = threadIdx.x & 63;
    int e0 = off[n], e1 = off[n + 1];
    float den[4] = {0, 0, 0, 0};
    float accA[4] = {0, 0, 0, 0};
    float accB[4] = {0, 0, 0, 0};
    int i = e0;
    for (; i + 3 < e1; i += 4) {
        int s0 = scsr[i], s1 = scsr[i + 1], s2 = scsr[i + 2], s3 = scsr[i + 3];
        float4 w0 = reinterpret_cast<const float4*>(wcsr)[i];
        float4 w1 = reinterpret_cast<const float4*>(wcsr)[i + 1];
        float4 w2 = reinterpret_cast<const float4*>(wcsr)[i + 2];
        float4 w3 = reinterpret_cast<const float4*>(wcsr)[i + 3];
        unsigned int u0 = hln[s0 * 64 + lane];
        unsigned int u1 = hln[s1 * 64 + lane];
        unsigned int u2 = hln[s2 * 64 + lane];
        unsigned int u3 = hln[s3 * 64 + lane];
        float f00 = __uint_as_float(u0 << 16), f01 = __uint_as_float(u0 & 0xffff0000u);
        float f10 = __uint_as_float(u1 << 16), f11 = __uint_as_float(u1 & 0xffff0000u);
        float f20 = __uint_as_float(u2 << 16), f21 = __uint_as_float(u2 & 0xffff0000u);
        float f30 = __uint_as_float(u3 << 16), f31 = __uint_as_float(u3 & 0xffff0000u);
        den[0] += (w0.x + w1.x) + (w2.x + w3.x);
        den[1] += (w0.y + w1.y) + (w2.y + w3.y);
        den[2] += (w0.z + w1.z) + (w2.z + w3.z);
        den[3] += (w0.w + w1.w) + (w2.w + w3.w);
        accA[0] += w0.x * f00 + w1.x * f10 + w2.x * f20 + w3.x * f30;
        accB[0] += w0.x * f01 + w1.x * f11 + w2.x * f21 + w3.x * f31;
        accA[1] += w0.y * f00 + w1.y * f10 + w2.y * f20 + w3.y * f30;
        accB[1] += w0.y * f01 + w1.y * f11 + w2.y * f21 + w3.y * f31;
        accA[2] += w0.z * f00 + w1.z * f10 + w2.z * f20 + w3.z * f30;
        accB[2] += w0.z * f01 + w1.z * f11 + w2.z * f21 + w3.z * f31;
        accA[3] += w0.w * f00 + w1.w * f10 + w2.w * f20 + w3.w * f30;
        accB[3] += w0.w * f01 + w1.w * f11 + w2.w * f21 + w3.w * f31;
    }
    for (; i < e1; ++i) {
        int s0 = scsr[i];
        float4 w0 = reinterpret_cast<const float4*>(wcsr)[i];
        unsigned int u0 = hln[s0 * 64 + lane];
        float f00 = __uint_as_float(u0 << 16);
        float f01 = __uint_as_float(u0 & 0xffff0000u);
        den[0] += w0.x; den[1] += w0.y; den[2] += w0.z; den[3] += w0.w;
        accA[0] += w0.x * f00; accB[0] += w0.x * f01;
        accA[1] += w0.y * f00; accB[1] += w0.y * f01;
        accA[2] += w0.z * f00; accB[2] += w0.z * f01;
        accA[3] += w0.w * f00; accB[3] += w0.w * f01;
    }
    #pragma unroll
    for (int h = 0; h < 4; ++h) {
        float inv = 1.f / (den[h] + 1e-16f);
        agg[n * 256 + h * 64 + lane] = packbf2(accA[h] * inv, accB[h] * inv);
    }
}

// ---------------- K=512 -> N=128 GEMM, double-buffered BK=64, A preloaded ----
template <bool LN>
__global__ __launch_bounds__(256) void k_qf(const short* __restrict__ A,
                                            const short* __restrict__ Bt,
                                            const float* __restrict__ bias,
                                            const float* __restrict__ resid,
                                            float* __restrict__ xout,
                                            const float* __restrict__ gma,
                                            const float* __restrict__ bta,
                                            __hip_bfloat16* __restrict__ hout,
                                            int M)
{
    __shared__ __align__(16) short Bls[2][128 * 64];   // 2 x 16 KB
    const int tid = threadIdx.x;
    const int lane = tid & 63;
    const int w = tid >> 6;
    const int lrow = lane & 15;
    const int lk = lane >> 4;
    const int mw = blockIdx.x * 64 + w * 16;

    // preload all A fragments (independent, overlap with staging)
    short8 aq[16];
    #pragma unroll
    for (int t = 0; t < 16; ++t)
        aq[t] = *reinterpret_cast<const short8*>(
            A + (size_t)(mw + lrow) * 512 + t * 32 + lk * 8);

    auto stage = [&](int buf, int kt) {
        #pragma unroll
        for (int c0 = 0; c0 < 1024; c0 += 256) {
            int c = c0 + tid;
            int wb = c0 + (w << 6);
            int r = c >> 3, gq = c & 7, gp = gq ^ (r & 7);
            gload_lds16(Bt + (size_t)r * 512 + kt + gp * 8, &Bls[buf][wb * 8]);
        }
    };

    f32x4 acc[8] = {};
    stage(0, 0);
    __syncthreads();
    int cur = 0;
    for (int t = 0; t < 8; ++t) {
        if (t < 7) stage(cur ^ 1, (t + 1) * 64);
        #pragma unroll
        for (int ks = 0; ks < 2; ++ks) {
            short8 af = aq[t * 2 + ks];
            short8 bf[8];
            #pragma unroll
            for (int fj = 0; fj < 8; ++fj) {
                int r = fj * 16 + lrow;
                int g = ks * 4 + lk;
                bf[fj] = *reinterpret_cast<const short8*>(
                    &Bls[cur][r * 64 + ((g ^ (r & 7)) * 8)]);
            }
            #pragma unroll
            for (int fj = 0; fj < 8; ++fj)
                acc[fj] = __builtin_amdgcn_mfma_f32_16x16x32_bf16(
                    af, bf[fj], acc[fj], 0, 0, 0);
        }
        __syncthreads();
        cur ^= 1;
    }

    #pragma unroll
    for (int p = 0; p < 4; ++p) {
        int m = mw + lk * 4 + p;
        float v[8], s = 0.f, sq = 0.f;
        #pragma unroll
        for (int fj = 0; fj < 8; ++fj) {
            int n = fj * 16 + lrow;
            v[fj] = acc[fj][p] + bias[n] + resid[(size_t)m * DIM + n];
            s += v[fj]; sq += v[fj] * v[fj];
        }
        #pragma unroll
        for (int fj = 0; fj < 8; ++fj)
            xout[(size_t)m * DIM + fj * 16 + lrow] = v[fj];
        if (LN) {
            #pragma unroll
            for (int d = 1; d < 16; d <<= 1) {
                s += __shfl_xor(s, d);
                sq += __shfl_xor(sq, d);
            }
            float mean = s * (1.f / DIM);
            float var = sq * (1.f / DIM) - mean * mean;
            float rs = rsqrtf(var + 1e-5f);
            #pragma unroll
            for (int fj = 0; fj < 8; ++fj) {
                int n = fj * 16 + lrow;
                hout[(size_t)m * DIM + n] =
                    __float2bfloat16((v[fj] - mean) * rs * gma[n] + bta[n]);
            }
        }
    }
}

// ---------------- fused FeedForward: BM=128 (32 rows/wave), 1 barrier/chunk,
//                  double-buffered weights, swapped GEMM1, packed mid writes --
template <bool LNN>
__global__ __launch_bounds__(256) void k_ff(const short* __restrict__ A,     // h_ln [M_PAD][128]
                                            const short* __restrict__ W1t,   // [512][128]
                                            const short* __restrict__ W2t,   // [128][512]
                                            const float* __restrict__ b1,
                                            const float* __restrict__ b2,
                                            const float* __restrict__ resid,
                                            float* __restrict__ xout,
                                            const float* __restrict__ gma,
                                            const float* __restrict__ bta,
                                            __hip_bfloat16* __restrict__ hout,
                                            const float* __restrict__ uvec,
                                            float* __restrict__ asrcO,
                                            float* __restrict__ adstO,
                                            int M)
{
    __shared__ __align__(16) short B1ls[2][64 * 128];  // 32 KB
    __shared__ __align__(16) short B2ls[2][128 * 64];  // 32 KB
    __shared__ __align__(16) short midls[4][32 * 64];  // 16 KB
    const int tid = threadIdx.x;
    const int lane = tid & 63;
    const int w = tid >> 6;
    const int lrow = lane & 15;
    const int lk = lane >> 4;
    const int mw = blockIdx.x * 128 + w * 32;
    short* midw = midls[w];

    short8 af[2][4];
    #pragma unroll
    for (int fi = 0; fi < 2; ++fi)
        #pragma unroll
        for (int ks = 0; ks < 4; ++ks)
            af[fi][ks] = *reinterpret_cast<const short8*>(
                A + (size_t)(mw + fi * 16 + lrow) * 128 + ks * 32 + lk * 8);

    auto stage1 = [&](int buf, int mc) {
        #pragma unroll
        for (int c0 = 0; c0 < 1024; c0 += 256) {
            int c = c0 + tid;
            int wb = c0 + (w << 6);
            int r = c >> 4, gq = c & 15, gp = gq ^ (r & 15);
            gload_lds16(W1t + (size_t)(mc * 64 + r) * 128 + gp * 8,
                        &B1ls[buf][wb * 8]);
        }
    };
    auto stage2 = [&](int buf, int mc) {
        #pragma unroll
        for (int c0 = 0; c0 < 1024; c0 += 256) {
            int c = c0 + tid;
            int wb = c0 + (w << 6);
            int r = c >> 3, gq = c & 7, gp = gq ^ (r & 7);
            gload_lds16(W2t + (size_t)r * 512 + mc * 64 + gp * 8,
                        &B2ls[buf][wb * 8]);
        }
    };

    f32x4 acc2[2][8] = {};
    stage1(0, 0);
    stage2(0, 0);
    for (int mc = 0; mc < 8; ++mc) {
        const int buf = mc & 1;
        __syncthreads();                    // staging for chunk mc complete
        if (mc < 7) { stage1(buf ^ 1, mc + 1); stage2(buf ^ 1, mc + 1); }
        // GEMM1 (swapped): acc1[fi][fj][p] = mid[fi*16+lrow][fj*16+lk*4+p]
        f32x4 acc1[2][4] = {};
        #pragma unroll
        for (int ks = 0; ks < 4; ++ks) {
            short8 bf1[4];
            #pragma unroll
            for (int fj = 0; fj < 4; ++fj) {
                int r = fj * 16 + lrow;
                bf1[fj] = *reinterpret_cast<const short8*>(
                    &B1ls[buf][r * 128 + (((ks * 4 + lk) ^ (r & 15)) * 8)]);
            }
            #pragma unroll
            for (int fi = 0; fi < 2; ++fi)
                #pragma unroll
                for (int fj = 0; fj < 4; ++fj)
                    acc1[fi][fj] = __builtin_amdgcn_mfma_f32_16x16x32_bf16(
                        bf1[fj], af[fi][ks], acc1[fi][fj], 0, 0, 0);
        }
        // gelu + bias -> packed 8B mid writes
        #pragma unroll
        for (int fi = 0; fi < 2; ++fi) {
            int mrow = fi * 16 + lrow;
            #pragma unroll
            for (int fj = 0; fj < 4; ++fj) {
                int cb = fj * 16 + lk * 4;
                float v0 = gelu_f(acc1[fi][fj][0] + b1[mc * 64 + cb + 0]);
                float v1 = gelu_f(acc1[fi][fj][1] + b1[mc * 64 + cb + 1]);
                float v2 = gelu_f(acc1[fi][fj][2] + b1[mc * 64 + cb + 2]);
                float v3 = gelu_f(acc1[fi][fj][3] + b1[mc * 64 + cb + 3]);
                int gw = cb >> 3;
                int addr = mrow * 64 + ((gw ^ (lrow & 7)) * 8) + (lk & 1) * 4;
                uint2 pk;
                pk.x = packbf2(v0, v1);
                pk.y = packbf2(v2, v3);
                *reinterpret_cast<uint2*>(&midw[addr]) = pk;
            }
        }
        // GEMM2: out += mid(32x64) @ W2chunk (intra-wave mid read, no barrier)
        #pragma unroll
        for (int ks2 = 0; ks2 < 2; ++ks2) {
            int g = ks2 * 4 + lk;
            short8 a2[2];
            #pragma unroll
            for (int fi = 0; fi < 2; ++fi)
                a2[fi] = *reinterpret_cast<const short8*>(
                    &midw[(fi * 16 + lrow) * 64 + ((g ^ (lrow & 7)) * 8)]);
            short8 bf2[8];
            #pragma unroll
            for (int fj = 0; fj < 8; ++fj) {
                int r = fj * 16 + lrow;
                bf2[fj] = *reinterpret_cast<const short8*>(
                    &B2ls[buf][r * 64 + ((g ^ (r & 7)) * 8)]);
            }
            #pragma unroll
            for (int fi = 0; fi < 2; ++fi)
                #pragma unroll
                for (int fj = 0; fj < 8; ++fj)
                    acc2[fi][fj] = __builtin_amdgcn_mfma_f32_16x16x32_bf16(
                        a2[fi], bf2[fj], acc2[fi][fj], 0, 0, 0);
        }
    }

    // uvec slice for fused dots (static indices -> registers)
    float uvv[8][8];
    if (LNN) {
        #pragma unroll
        for (int tt = 0; tt < 8; ++tt)
            #pragma unroll
            for (int fj = 0; fj < 8; ++fj)
                uvv[tt][fj] = uvec[tt * 128 + fj * 16 + lrow];
    }

    #pragma unroll
    for (int fi = 0; fi < 2; ++fi) {
        #pragma unroll
        for (int p = 0; p < 4; ++p) {
            int m = mw + fi * 16 + lk * 4 + p;
            bool ok = m < M;
            int ml = ok ? m : M - 1;
            float v[8], s = 0.f, sq = 0.f;
            #pragma unroll
            for (int fj = 0; fj < 8; ++fj) {
                int n = fj * 16 + lrow;
                v[fj] = acc2[fi][fj][p] + b2[n] + resid[(size_t)ml * DIM + n];
                s += v[fj]; sq += v[fj] * v[fj];
            }
            if (ok) {
                #pragma unroll
                for (int fj = 0; fj < 8; ++fj)
                    xout[(size_t)m * DIM + fj * 16 + lrow] = v[fj];
            }
            if (LNN) {
                #pragma unroll
                for (int d = 1; d < 16; d <<= 1) {
                    s += __shfl_xor(s, d);
                    sq += __shfl_xor(sq, d);
                }
                float mean = s * (1.f / DIM);
                float var = sq * (1.f / DIM) - mean * mean;
                float rs = rsqrtf(var + 1e-5f);
                float ss[8] = {0, 0, 0, 0, 0, 0, 0, 0};
                #pragma unroll
                for (int fj = 0; fj < 8; ++fj) {
                    int n = fj * 16 + lrow;
                    float h = (v[fj] - mean) * rs * gma[n] + bta[n];
                    if (ok) hout[(size_t)m * DIM + n] = __float2bfloat16(h);
                    #pragma unroll
                    for (int tt = 0; tt < 8; ++tt) ss[tt] += h * uvv[tt][fj];
                }
                #pragma unroll
                for (int d = 1; d < 16; d <<= 1) {
                    #pragma unroll
                    for (int tt = 0; tt < 8; ++tt) ss[tt] += __shfl_xor(ss[tt], d);
                }
                if (lrow == 0 && ok) {
                    reinterpret_cast<float4*>(asrcO)[m] =
                        make_float4(ss[0], ss[1], ss[2], ss[3]);
                    reinterpret_cast<float4*>(adstO)[m] =
                        make_float4(ss[4], ss[5], ss[6], ss[7]);
                }
            }
        }
    }
}

extern "C" void kernel_launch(void* const* d_in, const int* in_sizes, int n_in,
                              void* d_out, int out_size, void* d_ws, size_t ws_size,
                              hipStream_t stream)
{
    const float* x_in     = (const float*)d_in[0];
    const int*   ei       = (const int*)d_in[1];
    const float* ea       = (const float*)d_in[2];
    const float* ln1_g    = (const float*)d_in[3];
    const float* ln1_b    = (const float*)d_in[4];
    const float* gat_W    = (const float*)d_in[5];
    const float* att_src  = (const float*)d_in[6];
    const float* att_dst  = (const float*)d_in[7];
    const float* edge_W   = (const float*)d_in[8];
    const float* att_edge = (const float*)d_in[9];
    const float* gat_bias = (const float*)d_in[10];
    const float* qf_W     = (const float*)d_in[11];
    const float* qf_b     = (const float*)d_in[12];
    const float* ln2_g    = (const float*)d_in[13];
    const float* ln2_b    = (const float*)d_in[14];
    const float* ff_W1    = (const float*)d_in[15];
    const float* ff_b1    = (const float*)d_in[16];
    const float* ff_W2    = (const float*)d_in[17];
    const float* ff_b2    = (const float*)d_in[18];
    float* x = (float*)d_out;

    char* ws = (char*)d_ws;
    size_t o = 0;
    auto alloc = [&](size_t b) { size_t r = o; o += (b + 255) & ~(size_t)255; return r; };
    __hip_bfloat16*  h_ln  = (__hip_bfloat16*)(ws + alloc((size_t)M_PAD * DIM * 2));
    __hip_bfloat16*  gbuf  = (__hip_bfloat16*)(ws + alloc((size_t)N_NODES * HC * 2));
    float*           asrc  = (float*)(ws + alloc((size_t)N_NODES * 4 * 4));
    float*           adst  = (float*)(ws + alloc((size_t)N_NODES * 4 * 4));
    float*           ae4   = (float*)(ws + alloc(256));
    float*           uvec  = (float*)(ws + alloc((size_t)DEPTH_L * 1024 * 4));
    __hip_bfloat16*  Mt    = (__hip_bfloat16*)(ws + alloc((size_t)DEPTH_L * 65536 * 2));
    float*           cvec  = (float*)(ws + alloc(256 * 4));
    int*             deg   = (int*)(ws + alloc((size_t)(N_NODES + 1) * 4));
    int*             off   = (int*)(ws + alloc((size_t)(N_NODES + 1) * 4));
    int*             cur   = (int*)(ws + alloc((size_t)N_NODES * 4));
    int*             bsum  = (int*)(ws + alloc((size_t)(SCAN_NB + 1) * 4));
    int*             bpre  = (int*)(ws + alloc((size_t)(SCAN_NB + 1) * 4));
    int*             scsr  = (int*)(ws + alloc((size_t)N_EDGES * 4));
    int*             dcsr  = (int*)(ws + alloc((size_t)N_EDGES * 4));
    float*           eacsr = (float*)(ws + alloc((size_t)N_EDGES * 4));
    float*           wcsr  = (float*)(ws + alloc((size_t)N_EDGES * 4 * 4));
    __hip_bfloat16* Wt[DEPTH_L][2];
    for (int d = 0; d < DEPTH_L; ++d)
        for (int j = 0; j < 2; ++j)
            Wt[d][j] = (__hip_bfloat16*)(ws + alloc((size_t)65536 * 2));

    const int* srcA = ei;
    const int* dstA = ei + N_EDGES;

    // ---- merged prep ----
    PrepArgs pa;
    for (int d = 0; d < DEPTH_L; ++d) {
        pa.wsrc[d * 2 + 0] = ff_W1 + (size_t)d * DIM * MLP_DIM;
        pa.wK[d * 2 + 0] = DIM;     pa.wN[d * 2 + 0] = MLP_DIM;
        pa.wsrc[d * 2 + 1] = ff_W2 + (size_t)d * MLP_DIM * DIM;
        pa.wK[d * 2 + 1] = MLP_DIM; pa.wN[d * 2 + 1] = DIM;
        pa.wdst[d * 2 + 0] = Wt[d][0];
        pa.wdst[d * 2 + 1] = Wt[d][1];
    }
    pa.gat_W = gat_W; pa.att_src = att_src; pa.att_dst = att_dst;
    pa.edge_W = edge_W; pa.att_edge = att_edge;
    pa.gat_bias = gat_bias; pa.qf_W = qf_W; pa.qf_b = qf_b;
    pa.uvec = uvec; pa.Mt = Mt; pa.cvec = cvec; pa.ae = ae4;
    k_prep<<<1618, 256, 0, stream>>>(pa);

    // ---- CSR by dst (parallel scan, stream-ordered chain) ----
    hipMemsetAsync(deg, 0, (size_t)(N_NODES + 1) * 4, stream);
    k_hist<<<(N_EDGES + 255) / 256, 256, 0, stream>>>(dstA, deg);
    k_scan1<<<SCAN_NB, 256, 0, stream>>>(deg, off, bsum);
    k_scan2<<<1, 256, 0, stream>>>(bsum, bpre);
    k_scan3<<<SCAN_NB, 256, 0, stream>>>(off, bpre, cur);
    k_fill<<<(N_EDGES + 255) / 256, 256, 0, stream>>>(srcA, dstA, ea, cur, scsr, dcsr, eacsr);

    const int QB = N_NODES / 64;             // 625
    const int FB = (N_NODES + 127) / 128;    // 313
    const int NB = N_NODES / 4;              // 10000
    const int EB = (N_EDGES + 255) / 256;    // 1250

    // initial LayerNorm + fused dots
    k_ln<<<NB, 256, 0, stream>>>(x_in, ln1_g, ln1_b, uvec, h_ln, asrc, adst, N_NODES);

    for (int d = 0; d < DEPTH_L; ++d) {
        const float* resid0 = (d == 0) ? x_in : x;
        k_alpha<<<EB, 256, 0, stream>>>(scsr, dcsr, eacsr, asrc, adst, ae4 + d * 4, wcsr);
        k_agg2<<<NB, 256, 0, stream>>>(off, scsr, wcsr, (const unsigned int*)h_ln,
            (unsigned int*)gbuf);
        k_qf<true><<<QB, 256, 0, stream>>>((const short*)gbuf,
            (const short*)(Mt + (size_t)d * 65536), cvec + d * 128, resid0, x,
            ln2_g + d * DIM, ln2_b + d * DIM, h_ln, N_NODES);
        if (d + 1 < DEPTH_L) {
            k_ff<true><<<FB, 256, 0, stream>>>((const short*)h_ln,
                (const short*)Wt[d][0], (const short*)Wt[d][1],
                ff_b1 + d * MLP_DIM, ff_b2 + d * DIM, x, x,
                ln1_g + (d + 1) * DIM, ln1_b + (d + 1) * DIM, h_ln,
                uvec + (size_t)(d + 1) * 1024, asrc, adst, N_NODES);
        } else {
            k_ff<false><<<FB, 256, 0, stream>>>((const short*)h_ln,
                (const short*)Wt[d][0], (const short*)Wt[d][1],
                ff_b1 + d * MLP_DIM, ff_b2 + d * DIM, x, x,
                nullptr, nullptr, nullptr,
                nullptr, nullptr, nullptr, N_NODES);
        }
    }
}

// Round 19
// 261.626 us; speedup vs baseline: 1.0882x; 1.0882x over previous
//
#include <hip/hip_runtime.h>
#include <hip/hip_bf16.h>

#define N_NODES 40000
#define N_EDGES 320000
#define DIM 128
#define HC 512
#define NHEAD 4
#define CHEAD 128
#define DEPTH_L 2
#define MLP_DIM 512
#define SCAN_NB ((N_NODES + 255) / 256)   // 157

typedef __attribute__((ext_vector_type(8))) short short8;
typedef __attribute__((ext_vector_type(4))) float f32x4;

static __device__ __forceinline__ void gload_lds16(const void* g, void* l)
{
    __builtin_amdgcn_global_load_lds(
        (const __attribute__((address_space(1))) unsigned int*)g,
        (__attribute__((address_space(3))) unsigned int*)l,
        16, 0, 0);
}

static __device__ __forceinline__ unsigned int packbf2(float a, float b)
{
    union { __hip_bfloat16 h[2]; unsigned int u; } p;
    p.h[0] = __float2bfloat16(a);
    p.h[1] = __float2bfloat16(b);
    return p.u;
}

// fast gelu: v * sigmoid(2z), z = 0.7978845608(v + 0.044715 v^3)
static __device__ __forceinline__ float gelu_f(float v)
{
    float z2 = -1.5957691216f * (v + 0.044715f * v * v * v);
    return v / (1.f + __expf(z2));
}

// ---------------- merged prep: wcvt(1024) | prep_u(16) | prep_m(512) |
//                  prep_c(64) | ae(2)  = 1618 blocks --------------------------
struct PrepArgs {
    const float* wsrc[4];
    __hip_bfloat16* wdst[4];
    int wK[4];
    int wN[4];
    const float* gat_W;
    const float* att_src;
    const float* att_dst;
    const float* edge_W;
    const float* att_edge;
    const float* gat_bias;
    const float* qf_W;
    const float* qf_b;
    float* uvec;
    __hip_bfloat16* Mt;
    float* cvec;
    float* ae;
};
__global__ __launch_bounds__(256) void k_prep(PrepArgs a)
{
    int b = blockIdx.x;
    int tid = threadIdx.x;
    if (b < 1024) {                         // weight convert+transpose (FF)
        int j = b >> 8;
        int i = (b & 255) * 256 + tid;
        int K = a.wK[j], N = a.wN[j];
        if (i < K * N) {
            int n = i / K, k = i % K;
            a.wdst[j][i] = __float2bfloat16(a.wsrc[j][(size_t)k * N + n]);
        }
    } else if (b < 1040) {                  // uvec
        if (tid < 128) {
            int bb = b - 1024;
            int d = bb >> 3, t8 = bb & 7;
            int t = t8 >> 2, h = t8 & 3;
            int c = tid;
            const float* W = a.gat_W + (size_t)d * DIM * HC;
            const float* av = (t == 0 ? a.att_src : a.att_dst)
                              + (size_t)d * NHEAD * CHEAD + h * CHEAD;
            float s = 0.f;
            for (int cc = 0; cc < CHEAD; ++cc)
                s += W[(size_t)c * HC + h * CHEAD + cc] * av[cc];
            a.uvec[(size_t)d * 1024 + t8 * 128 + c] = s;
        }
    } else if (b < 1552) {                  // Mt
        int i = (b - 1040) * 256 + tid;     // [d][hk][j]
        int d = i >> 16;
        int hk = (i >> 7) & 511;
        int j = i & 127;
        int h = hk >> 7, k = hk & 127;
        const float* W = a.gat_W + (size_t)d * DIM * HC + (size_t)k * HC + h * CHEAD;
        const float* Q = a.qf_W + (size_t)d * HC * DIM + (size_t)h * CHEAD * DIM + j;
        float s = 0.f;
        for (int c = 0; c < CHEAD; ++c)
            s += W[c] * Q[(size_t)c * DIM];
        a.Mt[(size_t)d * 65536 + (size_t)j * 512 + hk] = __float2bfloat16(s);
    } else if (b < 1616) {                  // cvec
        int idx = (b - 1552) * 4 + (tid >> 6);
        int lane = tid & 63;
        int d = idx >> 7, j = idx & 127;
        float s = 0.f;
        for (int m = lane; m < HC; m += 64)
            s += a.gat_bias[(size_t)d * HC + m]
               * a.qf_W[(size_t)d * HC * DIM + (size_t)m * DIM + j];
        #pragma unroll
        for (int dd = 32; dd; dd >>= 1) s += __shfl_xor(s, dd);
        if (lane == 0) a.cvec[idx] = s + a.qf_b[(size_t)d * DIM + j];
    } else {                                // ae
        int d = b - 1616;
        int h = tid >> 6, lane = tid & 63;
        float2 w = *reinterpret_cast<const float2*>(
            a.edge_W + (size_t)d * HC + h * CHEAD + lane * 2);
        float2 av = *reinterpret_cast<const float2*>(
            a.att_edge + (size_t)d * NHEAD * CHEAD + h * CHEAD + lane * 2);
        float s = w.x * av.x + w.y * av.y;
        #pragma unroll
        for (int dd = 32; dd; dd >>= 1) s += __shfl_xor(s, dd);
        if (lane == 0) a.ae[d * 4 + h] = s;
    }
}

// ---------------- CSR build (parallel 3-pass scan; proven chain) -------------
__global__ void k_hist(const int* __restrict__ dst, int* __restrict__ deg)
{
    int e = blockIdx.x * 256 + threadIdx.x;
    if (e < N_EDGES) atomicAdd(&deg[dst[e]], 1);
}

__global__ __launch_bounds__(256) void k_scan1(const int* __restrict__ deg,
                                               int* __restrict__ off,
                                               int* __restrict__ bsum)
{
    __shared__ int wsum[4];
    int b = blockIdx.x;
    int t = threadIdx.x, lane = t & 63, w = t >> 6;
    int i = b * 256 + t;
    int v = (i < N_NODES) ? deg[i] : 0;
    int s = v;
    #pragma unroll
    for (int d = 1; d < 64; d <<= 1) {
        int u = __shfl_up(s, d);
        if (lane >= d) s += u;
    }
    if (lane == 63) wsum[w] = s;
    __syncthreads();
    int wpre = 0;
    #pragma unroll
    for (int j = 0; j < 4; ++j)
        if (j < w) wpre += wsum[j];
    if (i < N_NODES) off[i] = wpre + s - v;
    if (t == 255) bsum[b] = wpre + s;
}

__global__ __launch_bounds__(256) void k_scan2(int* __restrict__ bsum,
                                               int* __restrict__ bpre)
{
    __shared__ int wsum[4];
    int t = threadIdx.x, lane = t & 63, w = t >> 6;
    int v = (t < SCAN_NB) ? bsum[t] : 0;
    int s = v;
    #pragma unroll
    for (int d = 1; d < 64; d <<= 1) {
        int u = __shfl_up(s, d);
        if (lane >= d) s += u;
    }
    if (lane == 63) wsum[w] = s;
    __syncthreads();
    int wpre = 0;
    #pragma unroll
    for (int j = 0; j < 4; ++j)
        if (j < w) wpre += wsum[j];
    if (t < SCAN_NB) bpre[t] = wpre + s - v;
    if (t == 255) bpre[SCAN_NB] = wpre + s;   // grand total
}

__global__ __launch_bounds__(256) void k_scan3(int* __restrict__ off,
                                               const int* __restrict__ bpre,
                                               int* __restrict__ cur)
{
    int b = blockIdx.x;
    int i = b * 256 + threadIdx.x;
    if (i < N_NODES) {
        int o = off[i] + bpre[b];
        off[i] = o;
        cur[i] = o;
    }
    if (i == 0) off[N_NODES] = bpre[SCAN_NB];
}

__global__ void k_fill(const int* __restrict__ src, const int* __restrict__ dst,
                       const float* __restrict__ ea, int* __restrict__ cur,
                       int* __restrict__ scsr, int* __restrict__ dcsr,
                       float* __restrict__ eacsr)
{
    int e = blockIdx.x * 256 + threadIdx.x;
    if (e < N_EDGES) {
        int dd = dst[e];
        int p = atomicAdd(&cur[dd], 1);
        scsr[p] = src[e];
        dcsr[p] = dd;
        eacsr[p] = ea[e];
    }
}

// ---------------- LayerNorm + fused attention dots (initial) -----------------
__global__ __launch_bounds__(256) void k_ln(const float* __restrict__ x,
                                            const float* __restrict__ gma,
                                            const float* __restrict__ bta,
                                            const float* __restrict__ uvec,
                                            __hip_bfloat16* __restrict__ out,
                                            float* __restrict__ asrc,
                                            float* __restrict__ adst, int M)
{
    int row = blockIdx.x * 4 + (threadIdx.x >> 6);
    int lane = threadIdx.x & 63;
    if (row >= M) return;
    float2 v = *reinterpret_cast<const float2*>(x + (size_t)row * DIM + lane * 2);
    float s = v.x + v.y, sq = v.x * v.x + v.y * v.y;
    #pragma unroll
    for (int d = 32; d; d >>= 1) { s += __shfl_xor(s, d); sq += __shfl_xor(sq, d); }
    float mean = s * (1.f / DIM);
    float var = sq * (1.f / DIM) - mean * mean;
    float rs = rsqrtf(var + 1e-5f);
    int c = lane * 2;
    float h0 = (v.x - mean) * rs * gma[c] + bta[c];
    float h1 = (v.y - mean) * rs * gma[c + 1] + bta[c + 1];
    *reinterpret_cast<unsigned int*>(out + (size_t)row * DIM + c) = packbf2(h0, h1);
    // fused dots: 8 targets (4 src-heads, 4 dst-heads)
    float ss[8];
    #pragma unroll
    for (int tt = 0; tt < 8; ++tt) {
        float2 uv = *reinterpret_cast<const float2*>(uvec + tt * 128 + c);
        ss[tt] = h0 * uv.x + h1 * uv.y;
    }
    #pragma unroll
    for (int d = 32; d; d >>= 1) {
        #pragma unroll
        for (int tt = 0; tt < 8; ++tt) ss[tt] += __shfl_xor(ss[tt], d);
    }
    if (lane == 0) {
        reinterpret_cast<float4*>(asrc)[row] = make_float4(ss[0], ss[1], ss[2], ss[3]);
        reinterpret_cast<float4*>(adst)[row] = make_float4(ss[4], ss[5], ss[6], ss[7]);
    }
}

// ---------------- streaming per-edge weights (CSR order, coalesced) ----------
__global__ __launch_bounds__(256) void k_alpha(const int* __restrict__ scsr,
                                               const int* __restrict__ dcsr,
                                               const float* __restrict__ eacsr,
                                               const float* __restrict__ asrc,
                                               const float* __restrict__ adst,
                                               const float* __restrict__ ae4v,
                                               float* __restrict__ wcsr)
{
    int p = blockIdx.x * 256 + threadIdx.x;
    if (p >= N_EDGES) return;
    int s = scsr[p], dd = dcsr[p];
    float q = eacsr[p];
    float4 as = reinterpret_cast<const float4*>(asrc)[s];
    float4 ad = reinterpret_cast<const float4*>(adst)[dd];
    float4 ae = *reinterpret_cast<const float4*>(ae4v);
    float4 w;
    float al;
    al = as.x + ad.x + ae.x * q; al = al > 0.f ? al : 0.2f * al; w.x = __expf(al);
    al = as.y + ad.y + ae.y * q; al = al > 0.f ? al : 0.2f * al; w.y = __expf(al);
    al = as.z + ad.z + ae.z * q; al = al > 0.f ? al : 0.2f * al; w.z = __expf(al);
    al = as.w + ad.w + ae.w * q; al = al > 0.f ? al : 0.2f * al; w.w = __expf(al);
    reinterpret_cast<float4*>(wcsr)[p] = w;
}

// ---------------- input-space aggregate: 4 sequential edge chains in flight --
__global__ __launch_bounds__(256) void k_agg2(const int* __restrict__ off,
                                              const int* __restrict__ scsr,
                                              const float* __restrict__ wcsr,
                                              const unsigned int* __restrict__ hln,
                                              unsigned int* __restrict__ agg)
{
    int n = blockIdx.x * 4 + (threadIdx.x >> 6);
    int lane = threadIdx.x & 63;
    int e0 = off[n], e1 = off[n + 1];
    float den[4] = {0, 0, 0, 0};
    float accA[4] = {0, 0, 0, 0};
    float accB[4] = {0, 0, 0, 0};
    int i = e0;
    for (; i + 3 < e1; i += 4) {
        int s0 = scsr[i], s1 = scsr[i + 1], s2 = scsr[i + 2], s3 = scsr[i + 3];
        float4 w0 = reinterpret_cast<const float4*>(wcsr)[i];
        float4 w1 = reinterpret_cast<const float4*>(wcsr)[i + 1];
        float4 w2 = reinterpret_cast<const float4*>(wcsr)[i + 2];
        float4 w3 = reinterpret_cast<const float4*>(wcsr)[i + 3];
        unsigned int u0 = hln[s0 * 64 + lane];
        unsigned int u1 = hln[s1 * 64 + lane];
        unsigned int u2 = hln[s2 * 64 + lane];
        unsigned int u3 = hln[s3 * 64 + lane];
        float f00 = __uint_as_float(u0 << 16), f01 = __uint_as_float(u0 & 0xffff0000u);
        float f10 = __uint_as_float(u1 << 16), f11 = __uint_as_float(u1 & 0xffff0000u);
        float f20 = __uint_as_float(u2 << 16), f21 = __uint_as_float(u2 & 0xffff0000u);
        float f30 = __uint_as_float(u3 << 16), f31 = __uint_as_float(u3 & 0xffff0000u);
        den[0] += (w0.x + w1.x) + (w2.x + w3.x);
        den[1] += (w0.y + w1.y) + (w2.y + w3.y);
        den[2] += (w0.z + w1.z) + (w2.z + w3.z);
        den[3] += (w0.w + w1.w) + (w2.w + w3.w);
        accA[0] += w0.x * f00 + w1.x * f10 + w2.x * f20 + w3.x * f30;
        accB[0] += w0.x * f01 + w1.x * f11 + w2.x * f21 + w3.x * f31;
        accA[1] += w0.y * f00 + w1.y * f10 + w2.y * f20 + w3.y * f30;
        accB[1] += w0.y * f01 + w1.y * f11 + w2.y * f21 + w3.y * f31;
        accA[2] += w0.z * f00 + w1.z * f10 + w2.z * f20 + w3.z * f30;
        accB[2] += w0.z * f01 + w1.z * f11 + w2.z * f21 + w3.z * f31;
        accA[3] += w0.w * f00 + w1.w * f10 + w2.w * f20 + w3.w * f30;
        accB[3] += w0.w * f01 + w1.w * f11 + w2.w * f21 + w3.w * f31;
    }
    for (; i < e1; ++i) {
        int s0 = scsr[i];
        float4 w0 = reinterpret_cast<const float4*>(wcsr)[i];
        unsigned int u0 = hln[s0 * 64 + lane];
        float f00 = __uint_as_float(u0 << 16);
        float f01 = __uint_as_float(u0 & 0xffff0000u);
        den[0] += w0.x; den[1] += w0.y; den[2] += w0.z; den[3] += w0.w;
        accA[0] += w0.x * f00; accB[0] += w0.x * f01;
        accA[1] += w0.y * f00; accB[1] += w0.y * f01;
        accA[2] += w0.z * f00; accB[2] += w0.z * f01;
        accA[3] += w0.w * f00; accB[3] += w0.w * f01;
    }
    #pragma unroll
    for (int h = 0; h < 4; ++h) {
        float inv = 1.f / (den[h] + 1e-16f);
        agg[n * 256 + h * 64 + lane] = packbf2(accA[h] * inv, accB[h] * inv);
    }
}

// ---------------- K=512 -> N=128 GEMM, double-buffered BK=64, A preloaded ----
template <bool LN>
__global__ __launch_bounds__(256) void k_qf(const short* __restrict__ A,
                                            const short* __restrict__ Bt,
                                            const float* __restrict__ bias,
                                            const float* __restrict__ resid,
                                            float* __restrict__ xout,
                                            const float* __restrict__ gma,
                                            const float* __restrict__ bta,
                                            __hip_bfloat16* __restrict__ hout,
                                            int M)
{
    __shared__ __align__(16) short Bls[2][128 * 64];   // 2 x 16 KB
    const int tid = threadIdx.x;
    const int lane = tid & 63;
    const int w = tid >> 6;
    const int lrow = lane & 15;
    const int lk = lane >> 4;
    const int mw = blockIdx.x * 64 + w * 16;

    // preload all A fragments (independent, overlap with staging)
    short8 aq[16];
    #pragma unroll
    for (int t = 0; t < 16; ++t)
        aq[t] = *reinterpret_cast<const short8*>(
            A + (size_t)(mw + lrow) * 512 + t * 32 + lk * 8);

    auto stage = [&](int buf, int kt) {
        #pragma unroll
        for (int c0 = 0; c0 < 1024; c0 += 256) {
            int c = c0 + tid;
            int wb = c0 + (w << 6);
            int r = c >> 3, gq = c & 7, gp = gq ^ (r & 7);
            gload_lds16(Bt + (size_t)r * 512 + kt + gp * 8, &Bls[buf][wb * 8]);
        }
    };

    f32x4 acc[8] = {};
    stage(0, 0);
    __syncthreads();
    int cur = 0;
    for (int t = 0; t < 8; ++t) {
        if (t < 7) stage(cur ^ 1, (t + 1) * 64);
        #pragma unroll
        for (int ks = 0; ks < 2; ++ks) {
            short8 af = aq[t * 2 + ks];
            short8 bf[8];
            #pragma unroll
            for (int fj = 0; fj < 8; ++fj) {
                int r = fj * 16 + lrow;
                int g = ks * 4 + lk;
                bf[fj] = *reinterpret_cast<const short8*>(
                    &Bls[cur][r * 64 + ((g ^ (r & 7)) * 8)]);
            }
            #pragma unroll
            for (int fj = 0; fj < 8; ++fj)
                acc[fj] = __builtin_amdgcn_mfma_f32_16x16x32_bf16(
                    af, bf[fj], acc[fj], 0, 0, 0);
        }
        __syncthreads();
        cur ^= 1;
    }

    #pragma unroll
    for (int p = 0; p < 4; ++p) {
        int m = mw + lk * 4 + p;
        float v[8], s = 0.f, sq = 0.f;
        #pragma unroll
        for (int fj = 0; fj < 8; ++fj) {
            int n = fj * 16 + lrow;
            v[fj] = acc[fj][p] + bias[n] + resid[(size_t)m * DIM + n];
            s += v[fj]; sq += v[fj] * v[fj];
        }
        #pragma unroll
        for (int fj = 0; fj < 8; ++fj)
            xout[(size_t)m * DIM + fj * 16 + lrow] = v[fj];
        if (LN) {
            #pragma unroll
            for (int d = 1; d < 16; d <<= 1) {
                s += __shfl_xor(s, d);
                sq += __shfl_xor(sq, d);
            }
            float mean = s * (1.f / DIM);
            float var = sq * (1.f / DIM) - mean * mean;
            float rs = rsqrtf(var + 1e-5f);
            #pragma unroll
            for (int fj = 0; fj < 8; ++fj) {
                int n = fj * 16 + lrow;
                hout[(size_t)m * DIM + n] =
                    __float2bfloat16((v[fj] - mean) * rs * gma[n] + bta[n]);
            }
        }
    }
}

// ---------------- fused FeedForward (+ next LN1 + fused attention dots) ------
template <bool LNN>
__global__ __launch_bounds__(256) void k_ff(const short* __restrict__ A,     // h_ln [M][128]
                                            const short* __restrict__ W1t,   // [512][128]
                                            const short* __restrict__ W2t,   // [128][512]
                                            const float* __restrict__ b1,
                                            const float* __restrict__ b2,
                                            const float* __restrict__ resid,
                                            float* __restrict__ xout,
                                            const float* __restrict__ gma,
                                            const float* __restrict__ bta,
                                            __hip_bfloat16* __restrict__ hout,
                                            const float* __restrict__ uvec,
                                            float* __restrict__ asrcO,
                                            float* __restrict__ adstO,
                                            int M)
{
    __shared__ __align__(16) short B1ls[64 * 128];     // 16 KB
    __shared__ __align__(16) short B2ls[128 * 64];     // 16 KB
    __shared__ __align__(16) short midls[4][16 * 64];  // 8 KB
    const int tid = threadIdx.x;
    const int lane = tid & 63;
    const int w = tid >> 6;
    const int lrow = lane & 15;
    const int lk = lane >> 4;
    const int mw = blockIdx.x * 64 + w * 16;
    __hip_bfloat16* midw = (__hip_bfloat16*)midls[w];

    short8 af[4];
    #pragma unroll
    for (int ks = 0; ks < 4; ++ks)
        af[ks] = *reinterpret_cast<const short8*>(
            A + (size_t)(mw + lrow) * 128 + ks * 32 + lk * 8);

    auto stage1 = [&](int mc) {
        #pragma unroll
        for (int c0 = 0; c0 < 1024; c0 += 256) {
            int c = c0 + tid;
            int wb = c0 + (w << 6);
            int r = c >> 4, gq = c & 15, gp = gq ^ (r & 15);
            gload_lds16(W1t + (size_t)(mc * 64 + r) * 128 + gp * 8, &B1ls[wb * 8]);
        }
    };
    auto stage2 = [&](int mc) {
        #pragma unroll
        for (int c0 = 0; c0 < 1024; c0 += 256) {
            int c = c0 + tid;
            int wb = c0 + (w << 6);
            int r = c >> 3, gq = c & 7, gp = gq ^ (r & 7);
            gload_lds16(W2t + (size_t)r * 512 + mc * 64 + gp * 8, &B2ls[wb * 8]);
        }
    };

    f32x4 acc2[8] = {};
    stage1(0);
    for (int mc = 0; mc < 8; ++mc) {
        __syncthreads();
        stage2(mc);
        f32x4 acc1[4] = {};
        #pragma unroll
        for (int ks = 0; ks < 4; ++ks) {
            short8 bf1[4];
            #pragma unroll
            for (int fj = 0; fj < 4; ++fj) {
                int r = fj * 16 + lrow;
                bf1[fj] = *reinterpret_cast<const short8*>(
                    &B1ls[r * 128 + (((ks * 4 + lk) ^ (r & 15)) * 8)]);
            }
            #pragma unroll
            for (int fj = 0; fj < 4; ++fj)
                acc1[fj] = __builtin_amdgcn_mfma_f32_16x16x32_bf16(
                    af[ks], bf1[fj], acc1[fj], 0, 0, 0);
        }
        #pragma unroll
        for (int fj = 0; fj < 4; ++fj) {
            #pragma unroll
            for (int p = 0; p < 4; ++p) {
                int mloc = lk * 4 + p;
                int cloc = fj * 16 + lrow;
                float v = gelu_f(acc1[fj][p] + b1[mc * 64 + cloc]);
                int slot = (cloc >> 3) ^ (mloc & 7);
                midw[mloc * 64 + slot * 8 + (cloc & 7)] = __float2bfloat16(v);
            }
        }
        __syncthreads();
        if (mc < 7) stage1(mc + 1);
        #pragma unroll
        for (int ks2 = 0; ks2 < 2; ++ks2) {
            int g = ks2 * 4 + lk;
            short8 a2 = *reinterpret_cast<const short8*>(
                &midls[w][lrow * 64 + ((g ^ (lrow & 7)) * 8)]);
            short8 bf2[8];
            #pragma unroll
            for (int fj = 0; fj < 8; ++fj) {
                int r = fj * 16 + lrow;
                bf2[fj] = *reinterpret_cast<const short8*>(
                    &B2ls[r * 64 + ((g ^ (r & 7)) * 8)]);
            }
            #pragma unroll
            for (int fj = 0; fj < 8; ++fj)
                acc2[fj] = __builtin_amdgcn_mfma_f32_16x16x32_bf16(
                    a2, bf2[fj], acc2[fj], 0, 0, 0);
        }
    }

    // uvec slice for fused dots (static indices -> registers)
    float uvv[8][8];
    if (LNN) {
        #pragma unroll
        for (int tt = 0; tt < 8; ++tt)
            #pragma unroll
            for (int fj = 0; fj < 8; ++fj)
                uvv[tt][fj] = uvec[tt * 128 + fj * 16 + lrow];
    }

    #pragma unroll
    for (int p = 0; p < 4; ++p) {
        int m = mw + lk * 4 + p;
        float v[8], s = 0.f, sq = 0.f;
        #pragma unroll
        for (int fj = 0; fj < 8; ++fj) {
            int n = fj * 16 + lrow;
            v[fj] = acc2[fj][p] + b2[n] + resid[(size_t)m * DIM + n];
            s += v[fj]; sq += v[fj] * v[fj];
        }
        #pragma unroll
        for (int fj = 0; fj < 8; ++fj)
            xout[(size_t)m * DIM + fj * 16 + lrow] = v[fj];
        if (LNN) {
            #pragma unroll
            for (int d = 1; d < 16; d <<= 1) {
                s += __shfl_xor(s, d);
                sq += __shfl_xor(sq, d);
            }
            float mean = s * (1.f / DIM);
            float var = sq * (1.f / DIM) - mean * mean;
            float rs = rsqrtf(var + 1e-5f);
            float ss[8] = {0, 0, 0, 0, 0, 0, 0, 0};
            #pragma unroll
            for (int fj = 0; fj < 8; ++fj) {
                int n = fj * 16 + lrow;
                float h = (v[fj] - mean) * rs * gma[n] + bta[n];
                hout[(size_t)m * DIM + n] = __float2bfloat16(h);
                #pragma unroll
                for (int tt = 0; tt < 8; ++tt) ss[tt] += h * uvv[tt][fj];
            }
            #pragma unroll
            for (int d = 1; d < 16; d <<= 1) {
                #pragma unroll
                for (int tt = 0; tt < 8; ++tt) ss[tt] += __shfl_xor(ss[tt], d);
            }
            if (lrow == 0) {
                reinterpret_cast<float4*>(asrcO)[m] =
                    make_float4(ss[0], ss[1], ss[2], ss[3]);
                reinterpret_cast<float4*>(adstO)[m] =
                    make_float4(ss[4], ss[5], ss[6], ss[7]);
            }
        }
    }
}

extern "C" void kernel_launch(void* const* d_in, const int* in_sizes, int n_in,
                              void* d_out, int out_size, void* d_ws, size_t ws_size,
                              hipStream_t stream)
{
    const float* x_in     = (const float*)d_in[0];
    const int*   ei       = (const int*)d_in[1];
    const float* ea       = (const float*)d_in[2];
    const float* ln1_g    = (const float*)d_in[3];
    const float* ln1_b    = (const float*)d_in[4];
    const float* gat_W    = (const float*)d_in[5];
    const float* att_src  = (const float*)d_in[6];
    const float* att_dst  = (const float*)d_in[7];
    const float* edge_W   = (const float*)d_in[8];
    const float* att_edge = (const float*)d_in[9];
    const float* gat_bias = (const float*)d_in[10];
    const float* qf_W     = (const float*)d_in[11];
    const float* qf_b     = (const float*)d_in[12];
    const float* ln2_g    = (const float*)d_in[13];
    const float* ln2_b    = (const float*)d_in[14];
    const float* ff_W1    = (const float*)d_in[15];
    const float* ff_b1    = (const float*)d_in[16];
    const float* ff_W2    = (const float*)d_in[17];
    const float* ff_b2    = (const float*)d_in[18];
    float* x = (float*)d_out;

    char* ws = (char*)d_ws;
    size_t o = 0;
    auto alloc = [&](size_t b) { size_t r = o; o += (b + 255) & ~(size_t)255; return r; };
    __hip_bfloat16*  h_ln  = (__hip_bfloat16*)(ws + alloc((size_t)N_NODES * DIM * 2));
    __hip_bfloat16*  gbuf  = (__hip_bfloat16*)(ws + alloc((size_t)N_NODES * HC * 2));
    float*           asrc  = (float*)(ws + alloc((size_t)N_NODES * 4 * 4));
    float*           adst  = (float*)(ws + alloc((size_t)N_NODES * 4 * 4));
    float*           ae4   = (float*)(ws + alloc(256));
    float*           uvec  = (float*)(ws + alloc((size_t)DEPTH_L * 1024 * 4));
    __hip_bfloat16*  Mt    = (__hip_bfloat16*)(ws + alloc((size_t)DEPTH_L * 65536 * 2));
    float*           cvec  = (float*)(ws + alloc(256 * 4));
    int*             deg   = (int*)(ws + alloc((size_t)(N_NODES + 1) * 4));
    int*             off   = (int*)(ws + alloc((size_t)(N_NODES + 1) * 4));
    int*             cur   = (int*)(ws + alloc((size_t)N_NODES * 4));
    int*             bsum  = (int*)(ws + alloc((size_t)(SCAN_NB + 1) * 4));
    int*             bpre  = (int*)(ws + alloc((size_t)(SCAN_NB + 1) * 4));
    int*             scsr  = (int*)(ws + alloc((size_t)N_EDGES * 4));
    int*             dcsr  = (int*)(ws + alloc((size_t)N_EDGES * 4));
    float*           eacsr = (float*)(ws + alloc((size_t)N_EDGES * 4));
    float*           wcsr  = (float*)(ws + alloc((size_t)N_EDGES * 4 * 4));
    __hip_bfloat16* Wt[DEPTH_L][2];
    for (int d = 0; d < DEPTH_L; ++d)
        for (int j = 0; j < 2; ++j)
            Wt[d][j] = (__hip_bfloat16*)(ws + alloc((size_t)65536 * 2));

    const int* srcA = ei;
    const int* dstA = ei + N_EDGES;

    // ---- merged prep ----
    PrepArgs pa;
    for (int d = 0; d < DEPTH_L; ++d) {
        pa.wsrc[d * 2 + 0] = ff_W1 + (size_t)d * DIM * MLP_DIM;
        pa.wK[d * 2 + 0] = DIM;     pa.wN[d * 2 + 0] = MLP_DIM;
        pa.wsrc[d * 2 + 1] = ff_W2 + (size_t)d * MLP_DIM * DIM;
        pa.wK[d * 2 + 1] = MLP_DIM; pa.wN[d * 2 + 1] = DIM;
        pa.wdst[d * 2 + 0] = Wt[d][0];
        pa.wdst[d * 2 + 1] = Wt[d][1];
    }
    pa.gat_W = gat_W; pa.att_src = att_src; pa.att_dst = att_dst;
    pa.edge_W = edge_W; pa.att_edge = att_edge;
    pa.gat_bias = gat_bias; pa.qf_W = qf_W; pa.qf_b = qf_b;
    pa.uvec = uvec; pa.Mt = Mt; pa.cvec = cvec; pa.ae = ae4;
    k_prep<<<1618, 256, 0, stream>>>(pa);

    // ---- CSR by dst (parallel scan, stream-ordered chain) ----
    hipMemsetAsync(deg, 0, (size_t)(N_NODES + 1) * 4, stream);
    k_hist<<<(N_EDGES + 255) / 256, 256, 0, stream>>>(dstA, deg);
    k_scan1<<<SCAN_NB, 256, 0, stream>>>(deg, off, bsum);
    k_scan2<<<1, 256, 0, stream>>>(bsum, bpre);
    k_scan3<<<SCAN_NB, 256, 0, stream>>>(off, bpre, cur);
    k_fill<<<(N_EDGES + 255) / 256, 256, 0, stream>>>(srcA, dstA, ea, cur, scsr, dcsr, eacsr);

    const int QB = N_NODES / 64;            // 625
    const int NB = N_NODES / 4;             // 10000
    const int EB = (N_EDGES + 255) / 256;   // 1250

    // initial LayerNorm + fused dots
    k_ln<<<NB, 256, 0, stream>>>(x_in, ln1_g, ln1_b, uvec, h_ln, asrc, adst, N_NODES);

    for (int d = 0; d < DEPTH_L; ++d) {
        const float* resid0 = (d == 0) ? x_in : x;
        k_alpha<<<EB, 256, 0, stream>>>(scsr, dcsr, eacsr, asrc, adst, ae4 + d * 4, wcsr);
        k_agg2<<<NB, 256, 0, stream>>>(off, scsr, wcsr, (const unsigned int*)h_ln,
            (unsigned int*)gbuf);
        k_qf<true><<<QB, 256, 0, stream>>>((const short*)gbuf,
            (const short*)(Mt + (size_t)d * 65536), cvec + d * 128, resid0, x,
            ln2_g + d * DIM, ln2_b + d * DIM, h_ln, N_NODES);
        if (d + 1 < DEPTH_L) {
            k_ff<true><<<QB, 256, 0, stream>>>((const short*)h_ln,
                (const short*)Wt[d][0], (const short*)Wt[d][1],
                ff_b1 + d * MLP_DIM, ff_b2 + d * DIM, x, x,
                ln1_g + (d + 1) * DIM, ln1_b + (d + 1) * DIM, h_ln,
                uvec + (size_t)(d + 1) * 1024, asrc, adst, N_NODES);
        } else {
            k_ff<false><<<QB, 256, 0, stream>>>((const short*)h_ln,
                (const short*)Wt[d][0], (const short*)Wt[d][1],
                ff_b1 + d * MLP_DIM, ff_b2 + d * DIM, x, x,
                nullptr, nullptr, nullptr,
                nullptr, nullptr, nullptr, N_NODES);
        }
    }
}